// Round 20
// baseline (1649.495 us; speedup 1.0000x reference)
//
#include <hip/hip_runtime.h>
#include <hip/hip_bf16.h>
#include <hip/hip_cooperative_groups.h>
#include <math.h>

namespace cg = cooperative_groups;

#define Tt 64
#define Bb 32
#define Hh 512
#define EMBe 256
#define Ee 128
#define Ss 35
#define Vv 50257
#define Kk 896
#define TCc 32
#define VPAD 50304   // 393*128
#define NTILE 393

typedef __bf16 bf16_t;
typedef __bf16 bf16x4 __attribute__((ext_vector_type(4)));
typedef __bf16 bf16x8 __attribute__((ext_vector_type(8)));
typedef float f32x4 __attribute__((ext_vector_type(4)));

#define POIS32 0x7FC07FC0u

__device__ __forceinline__ float sigf(float x){ return 1.f/(1.f + expf(-x)); }

__device__ __forceinline__ void gll16(const void* g, void* l){
  __builtin_amdgcn_global_load_lds(
      (const __attribute__((address_space(1))) unsigned int*)g,
      (__attribute__((address_space(3))) unsigned int*)l, 16, 0, 0);
}

#define DOT4(acc, W_, H_) acc += (W_).x*(H_).x + (W_).y*(H_).y + (W_).z*(H_).z + (W_).w*(H_).w

// ---- K0a: condition embeddings -> enc rows 0..2  (enc layout [s][b][e])
__global__ void k_cond_emb(const int* __restrict__ cond, const float* __restrict__ t0,
                           const float* __restrict__ t1, const float* __restrict__ t2,
                           float* __restrict__ enc){
  int g = blockIdx.x*blockDim.x + threadIdx.x;
  if (g >= 3*Bb*Ee) return;
  int i = g/(Bb*Ee); int b = (g/Ee)%Bb; int e = g%Ee;
  const float* tbl = (i==0)? t0 : (i==1)? t1 : t2;
  int ci = cond[i*Bb + b];
  enc[(size_t)i*Bb*Ee + b*Ee + e] = tbl[(size_t)ci*Ee + e];
}

// ---- K0b
__global__ void k_cxw(const int* __restrict__ cond_seq, const float* __restrict__ cemb,
                      const float* __restrict__ Wih, const float* __restrict__ bih,
                      float* __restrict__ cxw){
  __shared__ float es[Ee];
  int row = blockIdx.x; int tid = threadIdx.x; // 128 threads
  int idx = cond_seq[row];
  es[tid] = cemb[(size_t)idx*Ee + tid];
  __syncthreads();
  const float4* hp = (const float4*)es;
  for (int q = 0; q < 3; ++q){
    int g = q*Ee + tid;
    const float4* wr = (const float4*)(Wih + (size_t)g*Ee);
    float acc = bih[g];
    #pragma unroll 8
    for (int k = 0; k < Ee/4; ++k){ float4 w4 = wr[k]; float4 h4 = hp[k]; DOT4(acc, w4, h4); }
    cxw[(size_t)row*(3*Ee) + g] = acc;
  }
}

// ---- x_emb gather -> bf16 [2048][256]
__global__ void k_xemb(const int* __restrict__ input_data, const float* __restrict__ emb,
                       bf16_t* __restrict__ xe){
  int row = blockIdx.x, tid = threadIdx.x; // 256 threads
  int idx = input_data[row];
  xe[(size_t)row*EMBe + tid] = (bf16_t)emb[(size_t)idx*EMBe + tid];
}

// ---- transpose cgru_Whh [384][128] -> WT [128][384]
__global__ void k_ctrans(const float* __restrict__ W, float* __restrict__ WT){
  int idx = blockIdx.x*256 + threadIdx.x;
  if (idx >= 3*Ee*Ee) return;
  int g = idx/Ee, k = idx%Ee;
  WT[(size_t)k*(3*Ee) + g] = W[idx];
}

// ---- K1: cseq GRU scan
__global__ void k_cseq_scan(const float* __restrict__ cxw, const float* __restrict__ WT,
                            const float* __restrict__ bhh, float* __restrict__ enc){
  __shared__ float hs[Ee];
  int b = blockIdx.x; int j = threadIdx.x; // 128 threads
  hs[j] = 0.f; __syncthreads();
  float b0 = bhh[j], b1 = bhh[Ee+j], b2 = bhh[2*Ee+j];
  for (int t = 0; t < TCc; ++t){
    const float* xp = cxw + ((size_t)t*Bb + b)*(3*Ee);
    float a0=b0, a1=b1, a2=b2;
    #pragma unroll 4
    for (int k = 0; k < Ee; ++k){
      float hk = hs[k];
      const float* wr = WT + (size_t)k*(3*Ee);
      a0 += hk * wr[j];
      a1 += hk * wr[Ee + j];
      a2 += hk * wr[2*Ee + j];
    }
    float r = sigf(xp[j] + a0);
    float z = sigf(xp[Ee + j] + a1);
    float n = tanhf(xp[2*Ee + j] + r*a2);
    float hcur = hs[j];
    float hn = (1.f - z)*n + z*hcur;
    __syncthreads();
    hs[j] = hn;
    enc[(size_t)(3+t)*Bb*Ee + b*Ee + j] = hn;
    __syncthreads();
  }
}

// ---- K2: enc_proj
__global__ void k_encproj(const float* __restrict__ enc, const float* __restrict__ attn_W,
                          float* __restrict__ enc_proj){
  __shared__ float es[Ee];
  int blk = blockIdx.x; int tid = threadIdx.x; // 256 threads, blk = b*35+s
  int b = blk/Ss, s = blk%Ss;
  if (tid < Ee) es[tid] = enc[(size_t)s*Bb*Ee + b*Ee + tid];
  __syncthreads();
  const float4* hp = (const float4*)es;
  for (int q = 0; q < 2; ++q){
    int hh = q*256 + tid;
    const float4* wr = (const float4*)(attn_W + (size_t)hh*(Ee+Hh));
    float acc = 0.f;
    #pragma unroll 8
    for (int k = 0; k < Ee/4; ++k){ float4 w4 = wr[k]; float4 h4 = hp[k]; DOT4(acc, w4, h4); }
    enc_proj[(size_t)blk*Hh + hh] = acc;
  }
}

#define HSLOT (Bb*Hh)          // bf16 elems per step buffer

// ---- poison hsteps: slot 0 -> zeros, slots 1..Tt -> bf16-NaN poison.
__global__ void k_poison(bf16_t* __restrict__ hsteps){
  size_t i = (size_t)blockIdx.x*256 + threadIdx.x;   // u32 word index
  size_t total = (size_t)(Tt+1)*HSLOT/2;
  if (i >= total) return;
  unsigned v = (i < HSLOT/2) ? 0u : POIS32;
  __hip_atomic_store((unsigned*)hsteps + i, v, __ATOMIC_RELAXED, __HIP_MEMORY_SCOPE_AGENT);
}

// ---- K3: cooperative main GRU scan. 128 blocks: 0..15 scan, 16..127 shadow W-convert.
//      Data-driven sync (poll NaN-poison) — deadlock-impossible.
#define SCAN_BLOCKS_L 128
#define SCAN_WORK 16
#define SCAN_THREADS 384
#define WSL_STRIDE 520
#define HST_STRIDE 520
#define GW_STRIDE 104
#define SCAN_LDS (96*WSL_STRIDE*2 + Bb*HST_STRIDE*2 + Bb*GW_STRIDE*4)
#define NCH 11   // ceil(4096/384)

__global__ __launch_bounds__(SCAN_THREADS) void k_scan_coop(
    const float* __restrict__ xw, const float* __restrict__ Whh,
    const float* __restrict__ bhh, float* __restrict__ h_all,
    bf16_t* __restrict__ hsteps, const float* __restrict__ Wd,
    bf16_t* __restrict__ Wb, int wbf){
  extern __shared__ char smem[];
  const int tid = threadIdx.x;
  const int blk = blockIdx.x;

  if (blk >= SCAN_WORK){
    if (wbf){
      size_t total = (size_t)VPAD*Kk/8;
      size_t stride = (size_t)(SCAN_BLOCKS_L - SCAN_WORK)*SCAN_THREADS;
      for (size_t c = (size_t)(blk - SCAN_WORK)*SCAN_THREADS + tid; c < total; c += stride){
        size_t i = c*8;
        size_t row = i / Kk;
        int col = (int)(i % Kk);
        bf16x8 o;
        if (row < Vv){
          float4 f0 = *(const float4*)(Wd + i);
          float4 f1 = *(const float4*)(Wd + i + 4);
          o[0]=(bf16_t)f0.x; o[1]=(bf16_t)f0.y; o[2]=(bf16_t)f0.z; o[3]=(bf16_t)f0.w;
          o[4]=(bf16_t)f1.x; o[5]=(bf16_t)f1.y; o[6]=(bf16_t)f1.z; o[7]=(bf16_t)f1.w;
        } else {
          #pragma unroll
          for (int k = 0; k < 8; ++k) o[k] = (bf16_t)0.f;
        }
        int kk = col >> 6, u = (col & 63) >> 3;
        int rs = (int)(row & 7);
        *(bf16x8*)(Wb + row*Kk + (kk << 6) + ((u ^ rs) << 3)) = o;
      }
    }
    return;
  }

  bf16_t* Wsl = (bf16_t*)smem;
  bf16_t* hst = (bf16_t*)(smem + 96*WSL_STRIDE*2);
  float*  gw  = (float*) (smem + 96*WSL_STRIDE*2 + Bb*HST_STRIDE*2);
  const int c0 = blk*32;

  for (int lr = 0; lr < 96; ++lr){
    int g = lr >> 5, i = lr & 31;
    const float* src = Whh + ((size_t)g*Hh + c0 + i)*Hh;
    for (int c = tid; c < Hh; c += SCAN_THREADS)
      Wsl[lr*WSL_STRIDE + c] = (bf16_t)src[c];
  }
  for (int idx = tid; idx < Bb*16; idx += SCAN_THREADS){
    int b = idx >> 4, u = idx & 15;
    float* hp = &h_all[(size_t)b*Hh + c0 + u*2];
    hp[0] = 0.f; hp[1] = 0.f;
  }

  const int npair = (tid < 128) ? 2 : 1;
  int pb[2], pc[2];
  float bh0[2][2], bh1[2][2], bh2[2][2], hreg[2][2];
  for (int p = 0; p < npair; ++p){
    int pid = tid + p*SCAN_THREADS;
    pb[p] = pid >> 4; pc[p] = (pid & 15)*2;
    for (int c = 0; c < 2; ++c){
      int j = c0 + pc[p] + c;
      bh0[p][c] = bhh[j]; bh1[p][c] = bhh[Hh + j]; bh2[p][c] = bhh[2*Hh + j];
      hreg[p][c] = 0.f;
    }
  }
  __syncthreads();

  const int wid = tid >> 6, lane = tid & 63;
  const int l15 = lane & 15, l4 = lane >> 4;

  for (int t = 0; t < Tt; ++t){
    {
      const unsigned long long* hinU = (const unsigned long long*)(hsteps + (size_t)t*HSLOT);
      unsigned long long v[NCH];
      int nmine = 0;
      #pragma unroll
      for (int k = 0; k < NCH; ++k){
        int idx = tid + k*SCAN_THREADS;
        if (idx < Bb*Hh/4){
          v[k] = __hip_atomic_load(hinU + idx, __ATOMIC_RELAXED, __HIP_MEMORY_SCOPE_AGENT);
          nmine = k + 1;
        }
      }
      #pragma unroll
      for (int k = 0; k < NCH; ++k){
        if (k < nmine){
          int idx = tid + k*SCAN_THREADS;
          while ((unsigned)v[k] == POIS32 || (unsigned)(v[k] >> 32) == POIS32){
            __builtin_amdgcn_s_sleep(1);
            v[k] = __hip_atomic_load(hinU + idx, __ATOMIC_RELAXED, __HIP_MEMORY_SCOPE_AGENT);
          }
        }
      }
      #pragma unroll
      for (int k = 0; k < NCH; ++k){
        if (k < nmine){
          int idx = tid + k*SCAN_THREADS;
          int b = idx >> 7, c4 = idx & 127;
          *((unsigned long long*)(hst + (size_t)b*HST_STRIDE) + c4) = v[k];
        }
      }
    }
    __syncthreads();

    f32x4 acc0 = {0.f,0.f,0.f,0.f}, acc1 = {0.f,0.f,0.f,0.f};
    #pragma unroll
    for (int ks = 0; ks < 16; ++ks){
      bf16x8 bfr = *(const bf16x8*)(Wsl + (wid*16 + l15)*WSL_STRIDE + ks*32 + l4*8);
      bf16x8 a0  = *(const bf16x8*)(hst + l15*HST_STRIDE        + ks*32 + l4*8);
      bf16x8 a1  = *(const bf16x8*)(hst + (16 + l15)*HST_STRIDE + ks*32 + l4*8);
      acc0 = __builtin_amdgcn_mfma_f32_16x16x32_bf16(a0, bfr, acc0, 0, 0, 0);
      acc1 = __builtin_amdgcn_mfma_f32_16x16x32_bf16(a1, bfr, acc1, 0, 0, 0);
    }
    #pragma unroll
    for (int i = 0; i < 4; ++i){
      gw[(l4*4 + i)*GW_STRIDE + wid*16 + l15]        = acc0[i];
      gw[(16 + l4*4 + i)*GW_STRIDE + wid*16 + l15]   = acc1[i];
    }
    __syncthreads();

    unsigned* houtU = (unsigned*)(hsteps + (size_t)(t+1)*HSLOT);
    for (int p = 0; p < npair; ++p){
      int b = pb[p], cl = pc[p];
      const float* xp = xw + ((size_t)t*Bb + b)*(3*Hh);
      float hn2[2];
      #pragma unroll
      for (int c = 0; c < 2; ++c){
        int j = c0 + cl + c;
        float gr = gw[b*GW_STRIDE + cl + c]      + bh0[p][c];
        float gz = gw[b*GW_STRIDE + 32 + cl + c] + bh1[p][c];
        float gn = gw[b*GW_STRIDE + 64 + cl + c] + bh2[p][c];
        float r = sigf(xp[j] + gr);
        float z = sigf(xp[Hh + j] + gz);
        float n = tanhf(xp[2*Hh + j] + r*gn);
        float hn = (1.f - z)*n + z*hreg[p][c];
        hreg[p][c] = hn; hn2[c] = hn;
      }
      unsigned u0 = (unsigned)__builtin_bit_cast(unsigned short, (bf16_t)hn2[0]);
      unsigned u1 = (unsigned)__builtin_bit_cast(unsigned short, (bf16_t)hn2[1]);
      __hip_atomic_store(houtU + ((b*Hh + c0 + cl) >> 1), u0 | (u1 << 16),
                         __ATOMIC_RELAXED, __HIP_MEMORY_SCOPE_AGENT);
    }
    for (int p = 0; p < npair; ++p){
      int b = pb[p], cl = pc[p];
      float* hp = &h_all[((size_t)(t+1)*Bb + b)*Hh + c0 + cl];
      hp[0] = hreg[p][0]; hp[1] = hreg[p][1];
    }
  }
}

// ---- generic MFMA GEMM: C[M=2048][N] = A_bf16[2048][KTOT] @ B_f32[N][LDB]^T + bias
#define SG_LDS (256*64*2)
#define SWZ(rowv, uv) (((size_t)(rowv))*64 + ((((uv) ^ ((rowv)&7)))<<3))

template<int KTOT, int LDB>
__global__ __launch_bounds__(256) void k_sgemm(const bf16_t* __restrict__ A,
                                               const float* __restrict__ B,
                                               const float* __restrict__ bias,
                                               float* __restrict__ C, int N){
  extern __shared__ char smem[];
  bf16_t* As = (bf16_t*)smem;
  bf16_t* Ws = As + 128*64;
  const int tid = threadIdx.x, bid = blockIdx.x;
  const int mt = bid & 15, nt = bid >> 4;
  const int m0 = mt*128, n0 = nt*128;
  const int srow = tid >> 1, sub = (tid & 1)*4;
  const int NKK2 = KTOT/64;

  int4 aR[4]; float4 wF[8];
#define SLOADA(KK) { \
    const int4* p = (const int4*)(A + (size_t)(m0 + srow)*KTOT + (KK)*64 + sub*8); \
    aR[0]=p[0]; aR[1]=p[1]; aR[2]=p[2]; aR[3]=p[3]; }
#define SLOADW(KK) { \
    const float4* p = (const float4*)(B + (size_t)(n0 + srow)*LDB + (KK)*64 + sub*8); \
    _Pragma("unroll") for (int r = 0; r < 8; ++r) wF[r] = p[r]; }
#define SSTORES() { \
    _Pragma("unroll") \
    for (int j = 0; j < 4; ++j) \
      *(int4*)(As + SWZ(srow, sub + j)) = aR[j]; \
    _Pragma("unroll") for (int j = 0; j < 4; ++j){ \
      bf16x8 p8; \
      p8[0]=(bf16_t)wF[2*j].x; p8[1]=(bf16_t)wF[2*j].y; p8[2]=(bf16_t)wF[2*j].z; p8[3]=(bf16_t)wF[2*j].w; \
      p8[4]=(bf16_t)wF[2*j+1].x; p8[5]=(bf16_t)wF[2*j+1].y; p8[6]=(bf16_t)wF[2*j+1].z; p8[7]=(bf16_t)wF[2*j+1].w; \
      *(bf16x8*)(Ws + SWZ(srow, sub + j)) = p8; \
    } }

  const int wave = tid >> 6, lane = tid & 63;
  const int l15 = lane & 15, l4 = lane >> 4;
  const int mh = (wave >> 1)*64, nh = (wave & 1)*64;

  f32x4 acc[4][4];
  #pragma unroll
  for (int i = 0; i < 4; ++i)
    #pragma unroll
    for (int j = 0; j < 4; ++j) acc[i][j] = (f32x4){0.f,0.f,0.f,0.f};

  SLOADA(0); SLOADW(0);
  SSTORES();
  __syncthreads();
  for (int kk = 0; kk < NKK2; ++kk){
    if (kk + 1 < NKK2){ SLOADA(kk + 1); SLOADW(kk + 1); }
    #pragma unroll
    for (int k32 = 0; k32 < 2; ++k32){
      const int u = k32*4 + l4;
      bf16x8 aF[4], bF[4];
      #pragma unroll
      for (int mf = 0; mf < 4; ++mf)
        aF[mf] = *(const bf16x8*)(As + SWZ(mh + mf*16 + l15, u));
      #pragma unroll
      for (int nf = 0; nf < 4; ++nf)
        bF[nf] = *(const bf16x8*)(Ws + SWZ(nh + nf*16 + l15, u));
      #pragma unroll
      for (int mf = 0; mf < 4; ++mf)
        #pragma unroll
        for (int nf = 0; nf < 4; ++nf)
          acc[mf][nf] = __builtin_amdgcn_mfma_f32_16x16x32_bf16(aF[mf], bF[nf], acc[mf][nf], 0, 0, 0);
    }
    __syncthreads();
    if (kk + 1 < NKK2){
      SSTORES();
      __syncthreads();
    }
  }
  #pragma unroll
  for (int mf = 0; mf < 4; ++mf){
    #pragma unroll
    for (int nf = 0; nf < 4; ++nf){
      int v = n0 + nh + nf*16 + l15;
      float bv = bias[v];
      int m = m0 + mh + mf*16 + l4*4;
      #pragma unroll
      for (int i = 0; i < 4; ++i)
        C[(size_t)(m + i)*N + v] = acc[mf][nf][i] + bv;
    }
  }
#undef SLOADA
#undef SLOADW
#undef SSTORES
}

// ---- K5: score + softmax + context
__global__ void k_score(const float* __restrict__ hw_attn, const float* __restrict__ enc_proj,
                        const float* __restrict__ enc, const float* __restrict__ vW,
                        float* __restrict__ w_out, float* __restrict__ c_all){
  __shared__ float hws[Hh];
  __shared__ float sc[Ss];
  __shared__ float wsm[Ss];
  int row = blockIdx.x, lane = threadIdx.x; // 64 threads
  int b = row & (Bb-1);
  for (int k = lane; k < Hh; k += 64) hws[k] = hw_attn[(size_t)row*Hh + k];
  __syncthreads();
  for (int s = 0; s < Ss; ++s){
    const float* ep = enc_proj + ((size_t)b*Ss + s)*Hh;
    float acc = 0.f;
    for (int k = lane; k < Hh; k += 64) acc += tanhf(ep[k] + hws[k]) * vW[k];
    #pragma unroll
    for (int off = 32; off > 0; off >>= 1) acc += __shfl_xor(acc, off);
    if (lane == 0) sc[s] = acc;
  }
  __syncthreads();
  float val = (lane < Ss) ? sc[lane] : -3.0e38f;
  float mx = val;
  #pragma unroll
  for (int off = 32; off > 0; off >>= 1) mx = fmaxf(mx, __shfl_xor(mx, off));
  float e = (lane < Ss) ? expf(val - mx) : 0.f;
  float sm = e;
  #pragma unroll
  for (int off = 32; off > 0; off >>= 1) sm += __shfl_xor(sm, off);
  float w = e / sm;
  if (lane < Ss){ w_out[(size_t)row*Ss + lane] = w; wsm[lane] = w; }
  __syncthreads();
  for (int q = 0; q < 2; ++q){
    int ee = q*64 + lane;
    float acc = 0.f;
    #pragma unroll
    for (int s = 0; s < Ss; ++s) acc += wsm[s]*enc[(size_t)s*Bb*Ee + b*Ee + ee];
    c_all[(size_t)row*Ee + ee] = acc;
  }
}

// ---- K6: build A (PRE-SWIZZLED: 16B unit u of each 64-elem K-chunk stored at u^(row&7))
__global__ void k_abuild(const int* __restrict__ input_data, const float* __restrict__ c_all,
                         const float* __restrict__ embedding, const float* __restrict__ h_all,
                         bf16_t* __restrict__ A){
  int row = blockIdx.x, tid = threadIdx.x; // 256 threads
  int xidx = input_data[row];
  bf16_t* Ar = A + (size_t)row*Kk;
  int rs = row & 7;
  for (int col = tid; col < Kk; col += 256){
    float v;
    if (col < Ee) v = c_all[(size_t)row*Ee + col];
    else if (col < Ee + EMBe) v = embedding[(size_t)xidx*EMBe + (col - Ee)];
    else v = h_all[(size_t)row*Hh + (col - Ee - EMBe)];
    int kk = col >> 6, u = (col & 63) >> 3, e = col & 7;
    Ar[(kk << 6) + ((u ^ rs) << 3) + e] = (bf16_t)v;
  }
}

// ---- K7 v9: 128x128x64, double-buffered global_load_lds, FUSED partial-LSE epilogue:
//      each block writes row-wise (max, sumexp) over its 128 cols to partials[row][nt].
#define BM 128
#define BN 128
#define BK 64
#define NKK (Kk/BK)
#define BUFSZ ((BM + BN)*BK)          // bf16 elems per buffer
#define GEMM_LDS (2*BUFSZ*2)          // 65536 B
#define NEGINF (-1.0e30f)

__device__ __forceinline__ void lse_comb(float& m, float& s, float om, float os){
  if (om > m){ s = s*expf(m - om) + os; m = om; }
  else        s = s + os*expf(om - m);
}

template<int WBF>
__global__ __launch_bounds__(256) void k_gemm7(const bf16_t* __restrict__ A,
                                               const void* __restrict__ Wsrc,
                                               const float* __restrict__ bias,
                                               float* __restrict__ out,
                                               float2* __restrict__ partials){
  extern __shared__ char smem[];
  const int tid = threadIdx.x;
  const int bid = blockIdx.x;
  const int mt = bid & 15, nt = bid >> 4;
  const int m0 = mt*BM, n0 = nt*BN;
  const int wave = tid >> 6, lane = tid & 63;
  const int l15 = lane & 15, l4 = lane >> 4;
  const int mh = (wave >> 1)*64, nh = (wave & 1)*64;

  f32x4 acc[4][4];
  #pragma unroll
  for (int i = 0; i < 4; ++i)
    #pragma unroll
    for (int j = 0; j < 4; ++j) acc[i][j] = (f32x4){0.f,0.f,0.f,0.f};

  if (WBF){
    const char* Ag = (const char*)A;
    const char* Wg = (const char*)Wsrc;
    bf16_t* bufs = (bf16_t*)smem;            // [2][BUFSZ]
    const int grow = tid >> 3;
    const size_t gcol = (size_t)(tid & 7)*16;
    {
      char* Asb = (char*)bufs;
      char* Wsb = Asb + BM*BK*2;
      #pragma unroll
      for (int j = 0; j < 4; ++j){
        gll16(Ag + (size_t)(m0 + j*32 + grow)*(Kk*2) + gcol, Asb + j*4096 + tid*16);
        gll16(Wg + (size_t)(n0 + j*32 + grow)*(Kk*2) + gcol, Wsb + j*4096 + tid*16);
      }
    }
    int cur = 0;
    for (int kk = 0; kk < NKK; ++kk){
      __syncthreads();
      if (kk + 1 < NKK){
        size_t ko = (size_t)(kk + 1)*128;
        char* Asb = (char*)(bufs + (cur ^ 1)*BUFSZ);
        char* Wsb = Asb + BM*BK*2;
        #pragma unroll
        for (int j = 0; j < 4; ++j){
          gll16(Ag + (size_t)(m0 + j*32 + grow)*(Kk*2) + ko + gcol, Asb + j*4096 + tid*16);
          gll16(Wg + (size_t)(n0 + j*32 + grow)*(Kk*2) + ko + gcol, Wsb + j*4096 + tid*16);
        }
      }
      const bf16_t* As = bufs + cur*BUFSZ;
      const bf16_t* Ws = As + BM*BK;
      #pragma unroll
      for (int k32 = 0; k32 < 2; ++k32){
        const int u = k32*4 + l4;
        bf16x8 aF[4], bF[4];
        #pragma unroll
        for (int mf = 0; mf < 4; ++mf)
          aF[mf] = *(const bf16x8*)(As + SWZ(mh + mf*16 + l15, u));
        #pragma unroll
        for (int nf = 0; nf < 4; ++nf)
          bF[nf] = *(const bf16x8*)(Ws + SWZ(nh + nf*16 + l15, u));
        #pragma unroll
        for (int mf = 0; mf < 4; ++mf)
          #pragma unroll
          for (int nf = 0; nf < 4; ++nf)
            acc[mf][nf] = __builtin_amdgcn_mfma_f32_16x16x32_bf16(aF[mf], bF[nf], acc[mf][nf], 0, 0, 0);
      }
      cur ^= 1;
    }
  } else {
    bf16_t* As = (bf16_t*)smem;
    bf16_t* Ws = As + BM*BK;
    const int srow = tid >> 1, sub = (tid & 1)*4;
    int4 aR[4]; float4 wF[8];
    const float* Wf = (const float*)Wsrc;
#define LOADA(KK) { \
    const int4* p = (const int4*)(A + (size_t)(m0 + srow)*Kk + (KK)*BK + sub*8); \
    aR[0]=p[0]; aR[1]=p[1]; aR[2]=p[2]; aR[3]=p[3]; }
#define LOADW(KK) { \
    int vrow = n0 + srow; \
    if (vrow < Vv){ \
      const float4* p = (const float4*)(Wf + (size_t)vrow*Kk + (KK)*BK + sub*8); \
      _Pragma("unroll") for (int r = 0; r < 8; ++r) wF[r] = p[r]; \
    } else { \
      _Pragma("unroll") for (int r = 0; r < 8; ++r) wF[r] = make_float4(0.f,0.f,0.f,0.f); \
    } }
#define STORES() { \
    _Pragma("unroll") \
    for (int j = 0; j < 4; ++j) \
      *(int4*)(As + (size_t)srow*64 + (size_t)(sub + j)*8) = aR[j]; \
    _Pragma("unroll") for (int j = 0; j < 4; ++j){ \
      bf16x8 p8; \
      p8[0]=(bf16_t)wF[2*j].x; p8[1]=(bf16_t)wF[2*j].y; p8[2]=(bf16_t)wF[2*j].z; p8[3]=(bf16_t)wF[2*j].w; \
      p8[4]=(bf16_t)wF[2*j+1].x; p8[5]=(bf16_t)wF[2*j+1].y; p8[6]=(bf16_t)wF[2*j+1].z; p8[7]=(bf16_t)wF[2*j+1].w; \
      *(bf16x8*)(Ws + SWZ(srow, sub + j)) = p8; \
    } }
    LOADA(0); LOADW(0);
    STORES();
    __syncthreads();
    for (int kk = 0; kk < NKK; ++kk){
      if (kk + 1 < NKK){ LOADA(kk + 1); LOADW(kk + 1); }
      #pragma unroll
      for (int k32 = 0; k32 < 2; ++k32){
        const int u = k32*4 + l4;
        bf16x8 aF[4], bF[4];
        #pragma unroll
        for (int mf = 0; mf < 4; ++mf)
          aF[mf] = *(const bf16x8*)(As + SWZ(mh + mf*16 + l15, u));
        #pragma unroll
        for (int nf = 0; nf < 4; ++nf)
          bF[nf] = *(const bf16x8*)(Ws + SWZ(nh + nf*16 + l15, u));
        #pragma unroll
        for (int mf = 0; mf < 4; ++mf)
          #pragma unroll
          for (int nf = 0; nf < 4; ++nf)
            acc[mf][nf] = __builtin_amdgcn_mfma_f32_16x16x32_bf16(aF[mf], bF[nf], acc[mf][nf], 0, 0, 0);
      }
      __syncthreads();
      if (kk + 1 < NKK){
        STORES();
        __syncthreads();
      }
    }
#undef LOADA
#undef LOADW
#undef STORES
  }
  // ---- epilogue: direct stores + fused partial-LSE.
  float bv4[4];
  #pragma unroll
  for (int nf = 0; nf < 4; ++nf){
    int v = n0 + nh + nf*16 + l15;
    bv4[nf] = (v < Vv) ? bias[v] : 0.f;
  }
  __syncthreads();   // main-loop LDS reads done; reuse smem for reduce buffer
  float2* epls = (float2*)smem;   // [128][2]
  #pragma unroll
  for (int mf = 0; mf < 4; ++mf){
    #pragma unroll
    for (int i = 0; i < 4; ++i){
      // thread's 4 values for row r = mh + mf*16 + l4*4 + i
      float vals[4]; float m = NEGINF;
      #pragma unroll
      for (int nf = 0; nf < 4; ++nf){
        int v = n0 + nh + nf*16 + l15;
        float x = acc[mf][nf][i] + bv4[nf];
        vals[nf] = (v < Vv) ? x : NEGINF;
        if (v < Vv){
          out[(size_t)(m0 + mh + mf*16 + l4*4 + i)*Vv + v] = x;
          if (vals[nf] > m) m = vals[nf];
        }
      }
      float s = 0.f;
      #pragma unroll
      for (int nf = 0; nf < 4; ++nf)
        if (vals[nf] > NEGINF) s += expf(vals[nf] - m);
      // reduce across the 16 lanes of this l4 group (l15 dimension)
      #pragma unroll
      for (int off = 1; off < 16; off <<= 1){
        float om = __shfl_xor(m, off);
        float os = __shfl_xor(s, off);
        lse_comb(m, s, om, os);
      }
      if (l15 == 0){
        int rl = mh + mf*16 + l4*4 + i;
        epls[rl*2 + (wave & 1)] = make_float2(m, s);
      }
    }
  }
  __syncthreads();
  if (tid < BM){
    float2 a = epls[tid*2 + 0];
    float2 b = epls[tid*2 + 1];
    float m = a.x, s = a.y;
    lse_comb(m, s, b.x, b.y);
    partials[(size_t)(m0 + tid)*512 + nt] = make_float2(m, s);
  }
}

// ---- K8b: combine per-tile partials -> lse[row]. One wave per row.
__global__ void k_lsecomb(const float2* __restrict__ partials, float* __restrict__ lse){
  int row = blockIdx.x*4 + (threadIdx.x >> 6);
  int lane = threadIdx.x & 63;
  const float2* p = partials + (size_t)row*512;
  float m = NEGINF, s = 0.f;
  for (int nt = lane; nt < NTILE; nt += 64){
    float2 v = p[nt];
    lse_comb(m, s, v.x, v.y);
  }
  #pragma unroll
  for (int off = 32; off > 0; off >>= 1){
    float om = __shfl_xor(m, off);
    float os = __shfl_xor(s, off);
    lse_comb(m, s, om, os);
  }
  if (lane == 0) lse[row] = m + logf(s);
}

// ---- K9: pred -= lse[row] (alignment-safe float4)
__global__ void k_sub(float* __restrict__ pred, const float* __restrict__ lse){
  int row = blockIdx.x, tid = threadIdx.x;
  float l = lse[row];
  float* p = pred + (size_t)row*Vv;
  int pre = (int)(((16 - (((size_t)p) & 15)) & 15) >> 2);
  if (tid < pre) p[tid] -= l;
  int n4 = (Vv - pre) >> 2;
  float4* p4 = (float4*)(p + pre);
  for (int v = tid; v < n4; v += 256){
    float4 x = p4[v];
    x.x -= l; x.y -= l; x.z -= l; x.w -= l;
    p4[v] = x;
  }
  int tl = pre + n4*4 + tid;
  if (tl < Vv) p[tl] -= l;
}

// ---- K10: copy hT
__global__ void k_hT(const float* __restrict__ h_all, float* __restrict__ hT){
  int g = blockIdx.x*256 + threadIdx.x;
  if (g < Bb*Hh) hT[g] = h_all[(size_t)Tt*Bb*Hh + g];
}

extern "C" void kernel_launch(void* const* d_in, const int* in_sizes, int n_in,
                              void* d_out, int out_size, void* d_ws, size_t ws_size,
                              hipStream_t stream){
  const int*   input_data = (const int*)d_in[0];
  const int*   condition  = (const int*)d_in[1];
  const int*   cond_seq   = (const int*)d_in[2];
  const float* emb_c0     = (const float*)d_in[3];
  const float* emb_c1     = (const float*)d_in[4];
  const float* emb_c2     = (const float*)d_in[5];
  const float* cseq_emb   = (const float*)d_in[6];
  const float* embedding  = (const float*)d_in[7];
  const float* attn_W     = (const float*)d_in[8];
  const float* attn_b     = (const float*)d_in[9];
  const float* v_W        = (const float*)d_in[10];
  const float* gru_Wih    = (const float*)d_in[11];
  const float* gru_Whh    = (const float*)d_in[12];
  const float* gru_bih    = (const float*)d_in[13];
  const float* gru_bhh    = (const float*)d_in[14];
  const float* cgru_Wih   = (const float*)d_in[15];
  const float* cgru_Whh   = (const float*)d_in[16];
  const float* cgru_bih   = (const float*)d_in[17];
  const float* cgru_bhh   = (const float*)d_in[18];
  const float* dense_W    = (const float*)d_in[19];
  const float* dense_b    = (const float*)d_in[20];

  float* out    = (float*)d_out;
  float* pred   = out;                              // [2048][V]
  float* hT_out = out + (size_t)Tt*Bb*Vv;           // [32][512]
  float* w_out  = hT_out + (size_t)Bb*Hh;           // [2048][35]

  float* ws       = (float*)d_ws;
  float* h_all    = ws;                                   // 65*32*512
  float* xw       = h_all + (size_t)(Tt+1)*Bb*Hh;         // 64*32*1536
  float* cxw      = xw + (size_t)Tt*Bb*3*Hh;              // 32*32*384
  float* enc      = cxw + (size_t)TCc*Bb*3*Ee;            // 35*32*128
  float* enc_proj = enc + (size_t)Ss*Bb*Ee;               // 32*35*512
  float* hw_attn  = enc_proj + (size_t)Bb*Ss*Hh;          // 64*32*512
  float* c_all    = hw_attn + (size_t)Tt*Bb*Hh;           // 64*32*128
  float* lse      = c_all + (size_t)Tt*Bb*Ee;             // 2048
  bf16_t* Abf     = (bf16_t*)(lse + Tt*Bb);               // 2048*896 bf16 (pre-swizzled)
  bf16_t* hsteps  = Abf + (size_t)Tt*Bb*Kk;               // 65*32*512 bf16 (per-step h)
  float* WTc      = (float*)(hsteps + (size_t)(Tt+1)*HSLOT); // 128*384 fp32
  int*   bar      = (int*)(WTc + 128*3*Ee);               // 256 ints (layout keep)
  float2* partials= (float2*)(bar + 256);                 // 2048*512 float2 (8 MB)
  bf16_t* xemb    = (bf16_t*)(partials + (size_t)Tt*Bb*512); // 2048*256 bf16
  bf16_t* Wb      = xemb + (size_t)Tt*Bb*EMBe;            // 50304*896 bf16 (pre-swizzled)
  size_t need_b   = (size_t)((char*)(Wb + (size_t)VPAD*Kk) - (char*)d_ws);
  bool use_wbf    = (ws_size >= need_b);

  k_cond_emb<<<48, 256, 0, stream>>>(condition, emb_c0, emb_c1, emb_c2, enc);
  k_cxw<<<TCc*Bb, 128, 0, stream>>>(cond_seq, cseq_emb, cgru_Wih, cgru_bih, cxw);
  k_xemb<<<Tt*Bb, 256, 0, stream>>>(input_data, embedding, xemb);
  k_sgemm<EMBe, EMBe><<<16*12, 256, SG_LDS, stream>>>(xemb, gru_Wih, gru_bih, xw, 3*Hh);
  k_ctrans<<<(3*Ee*Ee + 255)/256, 256, 0, stream>>>(cgru_Whh, WTc);
  k_cseq_scan<<<Bb, Ee, 0, stream>>>(cxw, WTc, cgru_bhh, enc);
  k_encproj<<<Bb*Ss, 256, 0, stream>>>(enc, attn_W, enc_proj);
  {
    int npb = (int)(((size_t)(Tt+1)*HSLOT/2 + 255)/256);
    k_poison<<<npb, 256, 0, stream>>>(hsteps);
  }

  (void)hipFuncSetAttribute((const void*)k_scan_coop, hipFuncAttributeMaxDynamicSharedMemorySize, SCAN_LDS);
  {
    void* xw_p = (void*)xw; void* whh_p = (void*)gru_Whh; void* bhh_p = (void*)gru_bhh;
    void* ha_p = (void*)h_all; void* hs_p = (void*)hsteps;
    void* wd_p = (void*)dense_W; void* wb_p = (void*)Wb;
    int wbf = use_wbf ? 1 : 0;
    void* args[] = {&xw_p, &whh_p, &bhh_p, &ha_p, &hs_p, &wd_p, &wb_p, &wbf};
    (void)hipLaunchCooperativeKernel((const void*)k_scan_coop, dim3(SCAN_BLOCKS_L), dim3(SCAN_THREADS),
                                     args, SCAN_LDS, stream);
  }

  // hw_attn GEMM: A = hsteps[0..63] (bf16 h before each step), B = attn_W[:, E:]
  k_sgemm<Hh, (Ee+Hh)><<<16*4, 256, SG_LDS, stream>>>(hsteps, attn_W + Ee, attn_b, hw_attn, Hh);
  k_score<<<Tt*Bb, 64, 0, stream>>>(hw_attn, enc_proj, enc, v_W, w_out, c_all);
  k_abuild<<<Tt*Bb, 256, 0, stream>>>(input_data, c_all, embedding, h_all, Abf);

  (void)hipFuncSetAttribute((const void*)k_gemm7<1>, hipFuncAttributeMaxDynamicSharedMemorySize, GEMM_LDS);
  (void)hipFuncSetAttribute((const void*)k_gemm7<0>, hipFuncAttributeMaxDynamicSharedMemorySize, GEMM_LDS);
  if (use_wbf){
    k_gemm7<1><<<16*((Vv + BN - 1)/BN), 256, GEMM_LDS, stream>>>(Abf, (const void*)Wb, dense_b, pred, partials);
  } else {
    k_gemm7<0><<<16*((Vv + BN - 1)/BN), 256, GEMM_LDS, stream>>>(Abf, (const void*)dense_W, dense_b, pred, partials);
  }

  k_lsecomb<<<Tt*Bb/4, 256, 0, stream>>>(partials, lse);
  k_sub<<<Tt*Bb, 256, 0, stream>>>(pred, lse);
  k_hT<<<64, 256, 0, stream>>>(h_all, hT_out);
}

// Round 21
// 1600.938 us; speedup vs baseline: 1.0303x; 1.0303x over previous
//
#include <hip/hip_runtime.h>
#include <hip/hip_bf16.h>
#include <hip/hip_cooperative_groups.h>
#include <math.h>

namespace cg = cooperative_groups;

#define Tt 64
#define Bb 32
#define Hh 512
#define EMBe 256
#define Ee 128
#define Ss 35
#define Vv 50257
#define Kk 896
#define TCc 32
#define VPAD 50304   // 393*128
#define NTILE 393

typedef __bf16 bf16_t;
typedef __bf16 bf16x4 __attribute__((ext_vector_type(4)));
typedef __bf16 bf16x8 __attribute__((ext_vector_type(8)));
typedef float f32x4 __attribute__((ext_vector_type(4)));

#define POIS32 0x7FC07FC0u

__device__ __forceinline__ float sigf(float x){ return 1.f/(1.f + expf(-x)); }

__device__ __forceinline__ void gll16(const void* g, void* l){
  __builtin_amdgcn_global_load_lds(
      (const __attribute__((address_space(1))) unsigned int*)g,
      (__attribute__((address_space(3))) unsigned int*)l, 16, 0, 0);
}

#define DOT4(acc, W_, H_) acc += (W_).x*(H_).x + (W_).y*(H_).y + (W_).z*(H_).z + (W_).w*(H_).w

// ---- K0a: condition embeddings -> enc rows 0..2  (enc layout [s][b][e])
__global__ void k_cond_emb(const int* __restrict__ cond, const float* __restrict__ t0,
                           const float* __restrict__ t1, const float* __restrict__ t2,
                           float* __restrict__ enc){
  int g = blockIdx.x*blockDim.x + threadIdx.x;
  if (g >= 3*Bb*Ee) return;
  int i = g/(Bb*Ee); int b = (g/Ee)%Bb; int e = g%Ee;
  const float* tbl = (i==0)? t0 : (i==1)? t1 : t2;
  int ci = cond[i*Bb + b];
  enc[(size_t)i*Bb*Ee + b*Ee + e] = tbl[(size_t)ci*Ee + e];
}

// ---- K0b
__global__ void k_cxw(const int* __restrict__ cond_seq, const float* __restrict__ cemb,
                      const float* __restrict__ Wih, const float* __restrict__ bih,
                      float* __restrict__ cxw){
  __shared__ float es[Ee];
  int row = blockIdx.x; int tid = threadIdx.x; // 128 threads
  int idx = cond_seq[row];
  es[tid] = cemb[(size_t)idx*Ee + tid];
  __syncthreads();
  const float4* hp = (const float4*)es;
  for (int q = 0; q < 3; ++q){
    int g = q*Ee + tid;
    const float4* wr = (const float4*)(Wih + (size_t)g*Ee);
    float acc = bih[g];
    #pragma unroll 8
    for (int k = 0; k < Ee/4; ++k){ float4 w4 = wr[k]; float4 h4 = hp[k]; DOT4(acc, w4, h4); }
    cxw[(size_t)row*(3*Ee) + g] = acc;
  }
}

// ---- x_emb gather -> bf16 [2048][256]
__global__ void k_xemb(const int* __restrict__ input_data, const float* __restrict__ emb,
                       bf16_t* __restrict__ xe){
  int row = blockIdx.x, tid = threadIdx.x; // 256 threads
  int idx = input_data[row];
  xe[(size_t)row*EMBe + tid] = (bf16_t)emb[(size_t)idx*EMBe + tid];
}

// ---- transpose cgru_Whh [384][128] -> WT [128][384]
__global__ void k_ctrans(const float* __restrict__ W, float* __restrict__ WT){
  int idx = blockIdx.x*256 + threadIdx.x;
  if (idx >= 3*Ee*Ee) return;
  int g = idx/Ee, k = idx%Ee;
  WT[(size_t)k*(3*Ee) + g] = W[idx];
}

// ---- K1: cseq GRU scan
__global__ void k_cseq_scan(const float* __restrict__ cxw, const float* __restrict__ WT,
                            const float* __restrict__ bhh, float* __restrict__ enc){
  __shared__ float hs[Ee];
  int b = blockIdx.x; int j = threadIdx.x; // 128 threads
  hs[j] = 0.f; __syncthreads();
  float b0 = bhh[j], b1 = bhh[Ee+j], b2 = bhh[2*Ee+j];
  for (int t = 0; t < TCc; ++t){
    const float* xp = cxw + ((size_t)t*Bb + b)*(3*Ee);
    float a0=b0, a1=b1, a2=b2;
    #pragma unroll 4
    for (int k = 0; k < Ee; ++k){
      float hk = hs[k];
      const float* wr = WT + (size_t)k*(3*Ee);
      a0 += hk * wr[j];
      a1 += hk * wr[Ee + j];
      a2 += hk * wr[2*Ee + j];
    }
    float r = sigf(xp[j] + a0);
    float z = sigf(xp[Ee + j] + a1);
    float n = tanhf(xp[2*Ee + j] + r*a2);
    float hcur = hs[j];
    float hn = (1.f - z)*n + z*hcur;
    __syncthreads();
    hs[j] = hn;
    enc[(size_t)(3+t)*Bb*Ee + b*Ee + j] = hn;
    __syncthreads();
  }
}

#define HSLOT (Bb*Hh)          // bf16 elems per step buffer

// ---- poison hsteps: slot 0 -> zeros, slots 1..Tt -> bf16-NaN poison.
__global__ void k_poison(bf16_t* __restrict__ hsteps){
  size_t i = (size_t)blockIdx.x*256 + threadIdx.x;   // u32 word index
  size_t total = (size_t)(Tt+1)*HSLOT/2;
  if (i >= total) return;
  unsigned v = (i < HSLOT/2) ? 0u : POIS32;
  __hip_atomic_store((unsigned*)hsteps + i, v, __ATOMIC_RELAXED, __HIP_MEMORY_SCOPE_AGENT);
}

// ---- K3: cooperative main GRU scan. 128 blocks: 0..15 scan, 16..127 shadow work
//      (encproj, then W fp32->bf16 pre-swizzled conversion). Data-driven sync.
#define SCAN_BLOCKS_L 128
#define SCAN_WORK 16
#define SCAN_THREADS 384
#define WSL_STRIDE 520
#define HST_STRIDE 520
#define GW_STRIDE 104
#define SCAN_LDS (96*WSL_STRIDE*2 + Bb*HST_STRIDE*2 + Bb*GW_STRIDE*4)
#define NCH 11   // ceil(4096/384)

__global__ __launch_bounds__(SCAN_THREADS) void k_scan_coop(
    const float* __restrict__ xw, const float* __restrict__ Whh,
    const float* __restrict__ bhh, float* __restrict__ h_all,
    bf16_t* __restrict__ hsteps, const float* __restrict__ Wd,
    bf16_t* __restrict__ Wb, int wbf,
    const float* __restrict__ enc, const float* __restrict__ attn_W,
    float* __restrict__ enc_proj){
  extern __shared__ char smem[];
  const int tid = threadIdx.x;
  const int blk = blockIdx.x;

  if (blk >= SCAN_WORK){
    // ---- shadow 1: enc_proj (enc ready pre-launch; consumer runs post-scan)
    {
      float* es = (float*)smem;   // 128 floats
      for (int item = blk - SCAN_WORK; item < Bb*Ss; item += SCAN_BLOCKS_L - SCAN_WORK){
        int b = item / Ss, s = item % Ss;
        __syncthreads();
        for (int e = tid; e < Ee; e += SCAN_THREADS) es[e] = enc[(size_t)s*Bb*Ee + b*Ee + e];
        __syncthreads();
        const float4* hp = (const float4*)es;
        for (int hh = tid; hh < Hh; hh += SCAN_THREADS){
          const float4* wr = (const float4*)(attn_W + (size_t)hh*(Ee+Hh));
          float acc = 0.f;
          #pragma unroll 8
          for (int k = 0; k < Ee/4; ++k){ float4 w4 = wr[k]; float4 h4 = hp[k]; DOT4(acc, w4, h4); }
          enc_proj[(size_t)item*Hh + hh] = acc;
        }
      }
    }
    // ---- shadow 2: W fp32 -> bf16 pre-swizzled (32-col chunks, unit u^(row&3))
    if (wbf){
      size_t total = (size_t)VPAD*Kk/8;
      size_t stride = (size_t)(SCAN_BLOCKS_L - SCAN_WORK)*SCAN_THREADS;
      for (size_t c = (size_t)(blk - SCAN_WORK)*SCAN_THREADS + tid; c < total; c += stride){
        size_t i = c*8;
        size_t row = i / Kk;
        int col = (int)(i % Kk);
        bf16x8 o;
        if (row < Vv){
          float4 f0 = *(const float4*)(Wd + i);
          float4 f1 = *(const float4*)(Wd + i + 4);
          o[0]=(bf16_t)f0.x; o[1]=(bf16_t)f0.y; o[2]=(bf16_t)f0.z; o[3]=(bf16_t)f0.w;
          o[4]=(bf16_t)f1.x; o[5]=(bf16_t)f1.y; o[6]=(bf16_t)f1.z; o[7]=(bf16_t)f1.w;
        } else {
          #pragma unroll
          for (int k = 0; k < 8; ++k) o[k] = (bf16_t)0.f;
        }
        int kk = col >> 5, u = (col & 31) >> 3;
        int rs = (int)(row & 3);
        *(bf16x8*)(Wb + row*Kk + (kk << 5) + ((u ^ rs) << 3)) = o;
      }
    }
    return;
  }

  bf16_t* Wsl = (bf16_t*)smem;
  bf16_t* hst = (bf16_t*)(smem + 96*WSL_STRIDE*2);
  float*  gw  = (float*) (smem + 96*WSL_STRIDE*2 + Bb*HST_STRIDE*2);
  const int c0 = blk*32;

  for (int lr = 0; lr < 96; ++lr){
    int g = lr >> 5, i = lr & 31;
    const float* src = Whh + ((size_t)g*Hh + c0 + i)*Hh;
    for (int c = tid; c < Hh; c += SCAN_THREADS)
      Wsl[lr*WSL_STRIDE + c] = (bf16_t)src[c];
  }
  for (int idx = tid; idx < Bb*16; idx += SCAN_THREADS){
    int b = idx >> 4, u = idx & 15;
    float* hp = &h_all[(size_t)b*Hh + c0 + u*2];
    hp[0] = 0.f; hp[1] = 0.f;
  }

  const int npair = (tid < 128) ? 2 : 1;
  int pb[2], pc[2];
  float bh0[2][2], bh1[2][2], bh2[2][2], hreg[2][2];
  for (int p = 0; p < npair; ++p){
    int pid = tid + p*SCAN_THREADS;
    pb[p] = pid >> 4; pc[p] = (pid & 15)*2;
    for (int c = 0; c < 2; ++c){
      int j = c0 + pc[p] + c;
      bh0[p][c] = bhh[j]; bh1[p][c] = bhh[Hh + j]; bh2[p][c] = bhh[2*Hh + j];
      hreg[p][c] = 0.f;
    }
  }
  __syncthreads();

  const int wid = tid >> 6, lane = tid & 63;
  const int l15 = lane & 15, l4 = lane >> 4;

  for (int t = 0; t < Tt; ++t){
    {
      const unsigned long long* hinU = (const unsigned long long*)(hsteps + (size_t)t*HSLOT);
      unsigned long long v[NCH];
      int nmine = 0;
      #pragma unroll
      for (int k = 0; k < NCH; ++k){
        int idx = tid + k*SCAN_THREADS;
        if (idx < Bb*Hh/4){
          v[k] = __hip_atomic_load(hinU + idx, __ATOMIC_RELAXED, __HIP_MEMORY_SCOPE_AGENT);
          nmine = k + 1;
        }
      }
      #pragma unroll
      for (int k = 0; k < NCH; ++k){
        if (k < nmine){
          int idx = tid + k*SCAN_THREADS;
          while ((unsigned)v[k] == POIS32 || (unsigned)(v[k] >> 32) == POIS32){
            __builtin_amdgcn_s_sleep(1);
            v[k] = __hip_atomic_load(hinU + idx, __ATOMIC_RELAXED, __HIP_MEMORY_SCOPE_AGENT);
          }
        }
      }
      #pragma unroll
      for (int k = 0; k < NCH; ++k){
        if (k < nmine){
          int idx = tid + k*SCAN_THREADS;
          int b = idx >> 7, c4 = idx & 127;
          *((unsigned long long*)(hst + (size_t)b*HST_STRIDE) + c4) = v[k];
        }
      }
    }
    __syncthreads();

    f32x4 acc0 = {0.f,0.f,0.f,0.f}, acc1 = {0.f,0.f,0.f,0.f};
    #pragma unroll
    for (int ks = 0; ks < 16; ++ks){
      bf16x8 bfr = *(const bf16x8*)(Wsl + (wid*16 + l15)*WSL_STRIDE + ks*32 + l4*8);
      bf16x8 a0  = *(const bf16x8*)(hst + l15*HST_STRIDE        + ks*32 + l4*8);
      bf16x8 a1  = *(const bf16x8*)(hst + (16 + l15)*HST_STRIDE + ks*32 + l4*8);
      acc0 = __builtin_amdgcn_mfma_f32_16x16x32_bf16(a0, bfr, acc0, 0, 0, 0);
      acc1 = __builtin_amdgcn_mfma_f32_16x16x32_bf16(a1, bfr, acc1, 0, 0, 0);
    }
    #pragma unroll
    for (int i = 0; i < 4; ++i){
      gw[(l4*4 + i)*GW_STRIDE + wid*16 + l15]        = acc0[i];
      gw[(16 + l4*4 + i)*GW_STRIDE + wid*16 + l15]   = acc1[i];
    }
    __syncthreads();

    unsigned* houtU = (unsigned*)(hsteps + (size_t)(t+1)*HSLOT);
    for (int p = 0; p < npair; ++p){
      int b = pb[p], cl = pc[p];
      const float* xp = xw + ((size_t)t*Bb + b)*(3*Hh);
      float hn2[2];
      #pragma unroll
      for (int c = 0; c < 2; ++c){
        int j = c0 + cl + c;
        float gr = gw[b*GW_STRIDE + cl + c]      + bh0[p][c];
        float gz = gw[b*GW_STRIDE + 32 + cl + c] + bh1[p][c];
        float gn = gw[b*GW_STRIDE + 64 + cl + c] + bh2[p][c];
        float r = sigf(xp[j] + gr);
        float z = sigf(xp[Hh + j] + gz);
        float n = tanhf(xp[2*Hh + j] + r*gn);
        float hn = (1.f - z)*n + z*hreg[p][c];
        hreg[p][c] = hn; hn2[c] = hn;
      }
      unsigned u0 = (unsigned)__builtin_bit_cast(unsigned short, (bf16_t)hn2[0]);
      unsigned u1 = (unsigned)__builtin_bit_cast(unsigned short, (bf16_t)hn2[1]);
      __hip_atomic_store(houtU + ((b*Hh + c0 + cl) >> 1), u0 | (u1 << 16),
                         __ATOMIC_RELAXED, __HIP_MEMORY_SCOPE_AGENT);
    }
    for (int p = 0; p < npair; ++p){
      int b = pb[p], cl = pc[p];
      float* hp = &h_all[((size_t)(t+1)*Bb + b)*Hh + c0 + cl];
      hp[0] = hreg[p][0]; hp[1] = hreg[p][1];
    }
  }
}

// ---- generic MFMA GEMM: C[M=2048][N] = A_bf16[2048][KTOT] @ B_f32[N][LDB]^T + bias
#define SG_LDS (256*64*2)
#define SWZ(rowv, uv) (((size_t)(rowv))*64 + ((((uv) ^ ((rowv)&7)))<<3))

template<int KTOT, int LDB>
__global__ __launch_bounds__(256) void k_sgemm(const bf16_t* __restrict__ A,
                                               const float* __restrict__ B,
                                               const float* __restrict__ bias,
                                               float* __restrict__ C, int N){
  extern __shared__ char smem[];
  bf16_t* As = (bf16_t*)smem;
  bf16_t* Ws = As + 128*64;
  const int tid = threadIdx.x, bid = blockIdx.x;
  const int mt = bid & 15, nt = bid >> 4;
  const int m0 = mt*128, n0 = nt*128;
  const int srow = tid >> 1, sub = (tid & 1)*4;
  const int NKK2 = KTOT/64;

  int4 aR[4]; float4 wF[8];
#define SLOADA(KK) { \
    const int4* p = (const int4*)(A + (size_t)(m0 + srow)*KTOT + (KK)*64 + sub*8); \
    aR[0]=p[0]; aR[1]=p[1]; aR[2]=p[2]; aR[3]=p[3]; }
#define SLOADW(KK) { \
    const float4* p = (const float4*)(B + (size_t)(n0 + srow)*LDB + (KK)*64 + sub*8); \
    _Pragma("unroll") for (int r = 0; r < 8; ++r) wF[r] = p[r]; }
#define SSTORES() { \
    _Pragma("unroll") \
    for (int j = 0; j < 4; ++j) \
      *(int4*)(As + SWZ(srow, sub + j)) = aR[j]; \
    _Pragma("unroll") for (int j = 0; j < 4; ++j){ \
      bf16x8 p8; \
      p8[0]=(bf16_t)wF[2*j].x; p8[1]=(bf16_t)wF[2*j].y; p8[2]=(bf16_t)wF[2*j].z; p8[3]=(bf16_t)wF[2*j].w; \
      p8[4]=(bf16_t)wF[2*j+1].x; p8[5]=(bf16_t)wF[2*j+1].y; p8[6]=(bf16_t)wF[2*j+1].z; p8[7]=(bf16_t)wF[2*j+1].w; \
      *(bf16x8*)(Ws + SWZ(srow, sub + j)) = p8; \
    } }

  const int wave = tid >> 6, lane = tid & 63;
  const int l15 = lane & 15, l4 = lane >> 4;
  const int mh = (wave >> 1)*64, nh = (wave & 1)*64;

  f32x4 acc[4][4];
  #pragma unroll
  for (int i = 0; i < 4; ++i)
    #pragma unroll
    for (int j = 0; j < 4; ++j) acc[i][j] = (f32x4){0.f,0.f,0.f,0.f};

  SLOADA(0); SLOADW(0);
  SSTORES();
  __syncthreads();
  for (int kk = 0; kk < NKK2; ++kk){
    if (kk + 1 < NKK2){ SLOADA(kk + 1); SLOADW(kk + 1); }
    #pragma unroll
    for (int k32 = 0; k32 < 2; ++k32){
      const int u = k32*4 + l4;
      bf16x8 aF[4], bF[4];
      #pragma unroll
      for (int mf = 0; mf < 4; ++mf)
        aF[mf] = *(const bf16x8*)(As + SWZ(mh + mf*16 + l15, u));
      #pragma unroll
      for (int nf = 0; nf < 4; ++nf)
        bF[nf] = *(const bf16x8*)(Ws + SWZ(nh + nf*16 + l15, u));
      #pragma unroll
      for (int mf = 0; mf < 4; ++mf)
        #pragma unroll
        for (int nf = 0; nf < 4; ++nf)
          acc[mf][nf] = __builtin_amdgcn_mfma_f32_16x16x32_bf16(aF[mf], bF[nf], acc[mf][nf], 0, 0, 0);
    }
    __syncthreads();
    if (kk + 1 < NKK2){
      SSTORES();
      __syncthreads();
    }
  }
  #pragma unroll
  for (int mf = 0; mf < 4; ++mf){
    #pragma unroll
    for (int nf = 0; nf < 4; ++nf){
      int v = n0 + nh + nf*16 + l15;
      float bv = bias[v];
      int m = m0 + mh + mf*16 + l4*4;
      #pragma unroll
      for (int i = 0; i < 4; ++i)
        C[(size_t)(m + i)*N + v] = acc[mf][nf][i] + bv;
    }
  }
#undef SLOADA
#undef SLOADW
#undef SSTORES
}

// ---- K5: score + softmax + context
__global__ void k_score(const float* __restrict__ hw_attn, const float* __restrict__ enc_proj,
                        const float* __restrict__ enc, const float* __restrict__ vW,
                        float* __restrict__ w_out, float* __restrict__ c_all){
  __shared__ float hws[Hh];
  __shared__ float sc[Ss];
  __shared__ float wsm[Ss];
  int row = blockIdx.x, lane = threadIdx.x; // 64 threads
  int b = row & (Bb-1);
  for (int k = lane; k < Hh; k += 64) hws[k] = hw_attn[(size_t)row*Hh + k];
  __syncthreads();
  for (int s = 0; s < Ss; ++s){
    const float* ep = enc_proj + ((size_t)b*Ss + s)*Hh;
    float acc = 0.f;
    for (int k = lane; k < Hh; k += 64) acc += tanhf(ep[k] + hws[k]) * vW[k];
    #pragma unroll
    for (int off = 32; off > 0; off >>= 1) acc += __shfl_xor(acc, off);
    if (lane == 0) sc[s] = acc;
  }
  __syncthreads();
  float val = (lane < Ss) ? sc[lane] : -3.0e38f;
  float mx = val;
  #pragma unroll
  for (int off = 32; off > 0; off >>= 1) mx = fmaxf(mx, __shfl_xor(mx, off));
  float e = (lane < Ss) ? expf(val - mx) : 0.f;
  float sm = e;
  #pragma unroll
  for (int off = 32; off > 0; off >>= 1) sm += __shfl_xor(sm, off);
  float w = e / sm;
  if (lane < Ss){ w_out[(size_t)row*Ss + lane] = w; wsm[lane] = w; }
  __syncthreads();
  for (int q = 0; q < 2; ++q){
    int ee = q*64 + lane;
    float acc = 0.f;
    #pragma unroll
    for (int s = 0; s < Ss; ++s) acc += wsm[s]*enc[(size_t)s*Bb*Ee + b*Ee + ee];
    c_all[(size_t)row*Ee + ee] = acc;
  }
}

// ---- K6: build A (PRE-SWIZZLED for BK=32: unit u of each 32-elem chunk at u^(row&3))
__global__ void k_abuild(const int* __restrict__ input_data, const float* __restrict__ c_all,
                         const float* __restrict__ embedding, const float* __restrict__ h_all,
                         bf16_t* __restrict__ A){
  int row = blockIdx.x, tid = threadIdx.x; // 256 threads
  int xidx = input_data[row];
  bf16_t* Ar = A + (size_t)row*Kk;
  int rs = row & 3;
  for (int col = tid; col < Kk; col += 256){
    float v;
    if (col < Ee) v = c_all[(size_t)row*Ee + col];
    else if (col < Ee + EMBe) v = embedding[(size_t)xidx*EMBe + (col - Ee)];
    else v = h_all[(size_t)row*Hh + (col - Ee - EMBe)];
    int kk = col >> 5, u = (col & 31) >> 3, e = col & 7;
    Ar[(kk << 5) + ((u ^ rs) << 3) + e] = (bf16_t)v;
  }
}

// ---- K7 v10: BK=32, 4-slot LDS ring, counted vmcnt (never 0 mid-loop) + raw s_barrier.
//      Fused partial-LSE epilogue (r20-verified).
#define BM 128
#define BN 128
#define BK2 32
#define NKKG (Kk/BK2)                 // 28
#define TILE_B ((BM + BN)*BK2)        // 8192 bf16 elems per ring slot (16 KB)
#define GEMM_LDS (4*TILE_B*2)         // 65536 B
#define NEGINF (-1.0e30f)

// [128][32] bf16 rows; unit u (8 bf16) stored at u^(row&3)
#define SWZ32(rowv, uv) (((size_t)(rowv))*32 + ((((uv) ^ ((rowv)&3)))<<3))

__device__ __forceinline__ void lse_comb(float& m, float& s, float om, float os){
  if (om > m){ s = s*expf(m - om) + os; m = om; }
  else        s = s + os*expf(om - m);
}

template<int WBF>
__global__ __launch_bounds__(256) void k_gemm7(const bf16_t* __restrict__ A,
                                               const void* __restrict__ Wsrc,
                                               const float* __restrict__ bias,
                                               float* __restrict__ out,
                                               float2* __restrict__ partials){
  extern __shared__ char smem[];
  const int tid = threadIdx.x;
  const int bid = blockIdx.x;
  const int mt = bid & 15, nt = bid >> 4;
  const int m0 = mt*BM, n0 = nt*BN;
  const int wave = tid >> 6, lane = tid & 63;
  const int l15 = lane & 15, l4 = lane >> 4;
  const int mh = (wave >> 1)*64, nh = (wave & 1)*64;

  f32x4 acc[4][4];
  #pragma unroll
  for (int i = 0; i < 4; ++i)
    #pragma unroll
    for (int j = 0; j < 4; ++j) acc[i][j] = (f32x4){0.f,0.f,0.f,0.f};

  if (WBF){
    const char* Ag = (const char*)A;
    const char* Wg = (const char*)Wsrc;
    bf16_t* ring = (bf16_t*)smem;   // [4][TILE_B]
    const int i0 = tid, i1 = tid + 256;   // 16B-unit indices (unit = row*4 + u)
    auto issue = [&](int t){
      char* Asb = (char*)(ring + (size_t)(t & 3)*TILE_B);
      char* Wsb = Asb + BM*BK2*2;
      size_t ko = (size_t)t*64;   // bytes: 32 bf16 per chunk
      gll16(Ag + (size_t)(m0 + (i0 >> 2))*(Kk*2) + ko + (size_t)(i0 & 3)*16, Asb + (size_t)i0*16);
      gll16(Ag + (size_t)(m0 + (i1 >> 2))*(Kk*2) + ko + (size_t)(i1 & 3)*16, Asb + (size_t)i1*16);
      gll16(Wg + (size_t)(n0 + (i0 >> 2))*(Kk*2) + ko + (size_t)(i0 & 3)*16, Wsb + (size_t)i0*16);
      gll16(Wg + (size_t)(n0 + (i1 >> 2))*(Kk*2) + ko + (size_t)(i1 & 3)*16, Wsb + (size_t)i1*16);
    };
    issue(0); issue(1); issue(2);
    for (int kk = 0; kk < NKKG; ++kk){
      __builtin_amdgcn_sched_barrier(0);
      if (kk + 2 < NKKG)      { asm volatile("s_waitcnt vmcnt(8)" ::: "memory"); }
      else if (kk + 1 < NKKG) { asm volatile("s_waitcnt vmcnt(4)" ::: "memory"); }
      else                    { asm volatile("s_waitcnt vmcnt(0)" ::: "memory"); }
      __builtin_amdgcn_sched_barrier(0);
      __builtin_amdgcn_s_barrier();
      __builtin_amdgcn_sched_barrier(0);
      if (kk + 3 < NKKG) issue(kk + 3);
      const bf16_t* As = ring + (size_t)(kk & 3)*TILE_B;
      const bf16_t* Ws = As + BM*BK2;
      bf16x8 aF[4], bF[4];
      #pragma unroll
      for (int mf = 0; mf < 4; ++mf)
        aF[mf] = *(const bf16x8*)(As + SWZ32(mh + mf*16 + l15, l4));
      #pragma unroll
      for (int nf = 0; nf < 4; ++nf)
        bF[nf] = *(const bf16x8*)(Ws + SWZ32(nh + nf*16 + l15, l4));
      #pragma unroll
      for (int mf = 0; mf < 4; ++mf)
        #pragma unroll
        for (int nf = 0; nf < 4; ++nf)
          acc[mf][nf] = __builtin_amdgcn_mfma_f32_16x16x32_bf16(aF[mf], bF[nf], acc[mf][nf], 0, 0, 0);
    }
  } else {
    // fallback: reg-staged, single buffer, 2 barriers/step. A global is pre-swizzled
    // (verbatim copy -> LDS linear); W fp32 converted and stored at swizzled position.
    bf16_t* As = (bf16_t*)smem;      // [128][32]
    bf16_t* Ws = As + BM*BK2;
    const int srow = tid >> 1, uh = (tid & 1)*2;  // units uh, uh+1
    int4 aR[2]; float4 wF[4];
    const float* Wf = (const float*)Wsrc;
#define LOADA(KK) { \
    const int4* p = (const int4*)(A + (size_t)(m0 + srow)*Kk + (KK)*BK2 + uh*8); \
    aR[0]=p[0]; aR[1]=p[1]; }
#define LOADW(KK) { \
    int vrow = n0 + srow; \
    if (vrow < Vv){ \
      const float4* p = (const float4*)(Wf + (size_t)vrow*Kk + (KK)*BK2 + uh*8); \
      _Pragma("unroll") for (int r = 0; r < 4; ++r) wF[r] = p[r]; \
    } else { \
      _Pragma("unroll") for (int r = 0; r < 4; ++r) wF[r] = make_float4(0.f,0.f,0.f,0.f); \
    } }
#define STORES() { \
    _Pragma("unroll") \
    for (int j = 0; j < 2; ++j) \
      *(int4*)(As + (size_t)srow*32 + (size_t)(uh + j)*8) = aR[j]; \
    _Pragma("unroll") for (int j = 0; j < 2; ++j){ \
      bf16x8 p8; \
      p8[0]=(bf16_t)wF[2*j].x; p8[1]=(bf16_t)wF[2*j].y; p8[2]=(bf16_t)wF[2*j].z; p8[3]=(bf16_t)wF[2*j].w; \
      p8[4]=(bf16_t)wF[2*j+1].x; p8[5]=(bf16_t)wF[2*j+1].y; p8[6]=(bf16_t)wF[2*j+1].z; p8[7]=(bf16_t)wF[2*j+1].w; \
      *(bf16x8*)(Ws + SWZ32(srow, uh + j)) = p8; \
    } }
    LOADA(0); LOADW(0);
    STORES();
    __syncthreads();
    for (int kk = 0; kk < NKKG; ++kk){
      if (kk + 1 < NKKG){ LOADA(kk + 1); LOADW(kk + 1); }
      bf16x8 aF[4], bF[4];
      #pragma unroll
      for (int mf = 0; mf < 4; ++mf)
        aF[mf] = *(const bf16x8*)(As + SWZ32(mh + mf*16 + l15, l4));
      #pragma unroll
      for (int nf = 0; nf < 4; ++nf)
        bF[nf] = *(const bf16x8*)(Ws + SWZ32(nh + nf*16 + l15, l4));
      #pragma unroll
      for (int mf = 0; mf < 4; ++mf)
        #pragma unroll
        for (int nf = 0; nf < 4; ++nf)
          acc[mf][nf] = __builtin_amdgcn_mfma_f32_16x16x32_bf16(aF[mf], bF[nf], acc[mf][nf], 0, 0, 0);
      __syncthreads();
      if (kk + 1 < NKKG){
        STORES();
        __syncthreads();
      }
    }
#undef LOADA
#undef LOADW
#undef STORES
  }
  // ---- epilogue: direct stores + fused partial-LSE (r20-verified).
  float bv4[4];
  #pragma unroll
  for (int nf = 0; nf < 4; ++nf){
    int v = n0 + nh + nf*16 + l15;
    bv4[nf] = (v < Vv) ? bias[v] : 0.f;
  }
  __syncthreads();   // main-loop LDS reads done; reuse smem for reduce buffer
  float2* epls = (float2*)smem;   // [128][2]
  #pragma unroll
  for (int mf = 0; mf < 4; ++mf){
    #pragma unroll
    for (int i = 0; i < 4; ++i){
      float vals[4]; float m = NEGINF;
      #pragma unroll
      for (int nf = 0; nf < 4; ++nf){
        int v = n0 + nh + nf*16 + l15;
        float x = acc[mf][nf][i] + bv4[nf];
        vals[nf] = (v < Vv) ? x : NEGINF;
        if (v < Vv){
          out[(size_t)(m0 + mh + mf*16 + l4*4 + i)*Vv + v] = x;
          if (vals[nf] > m) m = vals[nf];
        }
      }
      float s = 0.f;
      #pragma unroll
      for (int nf = 0; nf < 4; ++nf)
        if (vals[nf] > NEGINF) s += expf(vals[nf] - m);
      #pragma unroll
      for (int off = 1; off < 16; off <<= 1){
        float om = __shfl_xor(m, off);
        float os = __shfl_xor(s, off);
        lse_comb(m, s, om, os);
      }
      if (l15 == 0){
        int rl = mh + mf*16 + l4*4 + i;
        epls[rl*2 + (wave & 1)] = make_float2(m, s);
      }
    }
  }
  __syncthreads();
  if (tid < BM){
    float2 a = epls[tid*2 + 0];
    float2 b = epls[tid*2 + 1];
    float m = a.x, s = a.y;
    lse_comb(m, s, b.x, b.y);
    partials[(size_t)(m0 + tid)*512 + nt] = make_float2(m, s);
  }
}

// ---- K8b: combine per-tile partials -> lse[row]. One wave per row.
__global__ void k_lsecomb(const float2* __restrict__ partials, float* __restrict__ lse){
  int row = blockIdx.x*4 + (threadIdx.x >> 6);
  int lane = threadIdx.x & 63;
  const float2* p = partials + (size_t)row*512;
  float m = NEGINF, s = 0.f;
  for (int nt = lane; nt < NTILE; nt += 64){
    float2 v = p[nt];
    lse_comb(m, s, v.x, v.y);
  }
  #pragma unroll
  for (int off = 32; off > 0; off >>= 1){
    float om = __shfl_xor(m, off);
    float os = __shfl_xor(s, off);
    lse_comb(m, s, om, os);
  }
  if (lane == 0) lse[row] = m + logf(s);
}

// ---- K9: pred -= lse[row] (alignment-safe float4)
__global__ void k_sub(float* __restrict__ pred, const float* __restrict__ lse){
  int row = blockIdx.x, tid = threadIdx.x;
  float l = lse[row];
  float* p = pred + (size_t)row*Vv;
  int pre = (int)(((16 - (((size_t)p) & 15)) & 15) >> 2);
  if (tid < pre) p[tid] -= l;
  int n4 = (Vv - pre) >> 2;
  float4* p4 = (float4*)(p + pre);
  for (int v = tid; v < n4; v += 256){
    float4 x = p4[v];
    x.x -= l; x.y -= l; x.z -= l; x.w -= l;
    p4[v] = x;
  }
  int tl = pre + n4*4 + tid;
  if (tl < Vv) p[tl] -= l;
}

// ---- K10: copy hT
__global__ void k_hT(const float* __restrict__ h_all, float* __restrict__ hT){
  int g = blockIdx.x*256 + threadIdx.x;
  if (g < Bb*Hh) hT[g] = h_all[(size_t)Tt*Bb*Hh + g];
}

extern "C" void kernel_launch(void* const* d_in, const int* in_sizes, int n_in,
                              void* d_out, int out_size, void* d_ws, size_t ws_size,
                              hipStream_t stream){
  const int*   input_data = (const int*)d_in[0];
  const int*   condition  = (const int*)d_in[1];
  const int*   cond_seq   = (const int*)d_in[2];
  const float* emb_c0     = (const float*)d_in[3];
  const float* emb_c1     = (const float*)d_in[4];
  const float* emb_c2     = (const float*)d_in[5];
  const float* cseq_emb   = (const float*)d_in[6];
  const float* embedding  = (const float*)d_in[7];
  const float* attn_W     = (const float*)d_in[8];
  const float* attn_b     = (const float*)d_in[9];
  const float* v_W        = (const float*)d_in[10];
  const float* gru_Wih    = (const float*)d_in[11];
  const float* gru_Whh    = (const float*)d_in[12];
  const float* gru_bih    = (const float*)d_in[13];
  const float* gru_bhh    = (const float*)d_in[14];
  const float* cgru_Wih   = (const float*)d_in[15];
  const float* cgru_Whh   = (const float*)d_in[16];
  const float* cgru_bih   = (const float*)d_in[17];
  const float* cgru_bhh   = (const float*)d_in[18];
  const float* dense_W    = (const float*)d_in[19];
  const float* dense_b    = (const float*)d_in[20];

  float* out    = (float*)d_out;
  float* pred   = out;                              // [2048][V]
  float* hT_out = out + (size_t)Tt*Bb*Vv;           // [32][512]
  float* w_out  = hT_out + (size_t)Bb*Hh;           // [2048][35]

  float* ws       = (float*)d_ws;
  float* h_all    = ws;                                   // 65*32*512
  float* xw       = h_all + (size_t)(Tt+1)*Bb*Hh;         // 64*32*1536
  float* cxw      = xw + (size_t)Tt*Bb*3*Hh;              // 32*32*384
  float* enc      = cxw + (size_t)TCc*Bb*3*Ee;            // 35*32*128
  float* enc_proj = enc + (size_t)Ss*Bb*Ee;               // 32*35*512
  float* hw_attn  = enc_proj + (size_t)Bb*Ss*Hh;          // 64*32*512
  float* c_all    = hw_attn + (size_t)Tt*Bb*Hh;           // 64*32*128
  float* lse      = c_all + (size_t)Tt*Bb*Ee;             // 2048
  bf16_t* Abf     = (bf16_t*)(lse + Tt*Bb);               // 2048*896 bf16 (pre-swizzled)
  bf16_t* hsteps  = Abf + (size_t)Tt*Bb*Kk;               // 65*32*512 bf16 (per-step h)
  float* WTc      = (float*)(hsteps + (size_t)(Tt+1)*HSLOT); // 128*384 fp32
  int*   bar      = (int*)(WTc + 128*3*Ee);               // 256 ints (layout keep)
  float2* partials= (float2*)(bar + 256);                 // 2048*512 float2 (8 MB)
  bf16_t* xemb    = (bf16_t*)(partials + (size_t)Tt*Bb*512); // 2048*256 bf16
  bf16_t* Wb      = xemb + (size_t)Tt*Bb*EMBe;            // 50304*896 bf16 (pre-swizzled)
  size_t need_b   = (size_t)((char*)(Wb + (size_t)VPAD*Kk) - (char*)d_ws);
  bool use_wbf    = (ws_size >= need_b);

  k_cond_emb<<<48, 256, 0, stream>>>(condition, emb_c0, emb_c1, emb_c2, enc);
  k_cxw<<<TCc*Bb, 128, 0, stream>>>(cond_seq, cseq_emb, cgru_Wih, cgru_bih, cxw);
  k_xemb<<<Tt*Bb, 256, 0, stream>>>(input_data, embedding, xemb);
  k_sgemm<EMBe, EMBe><<<16*12, 256, SG_LDS, stream>>>(xemb, gru_Wih, gru_bih, xw, 3*Hh);
  k_ctrans<<<(3*Ee*Ee + 255)/256, 256, 0, stream>>>(cgru_Whh, WTc);
  k_cseq_scan<<<Bb, Ee, 0, stream>>>(cxw, WTc, cgru_bhh, enc);
  {
    int npb = (int)(((size_t)(Tt+1)*HSLOT/2 + 255)/256);
    k_poison<<<npb, 256, 0, stream>>>(hsteps);
  }

  (void)hipFuncSetAttribute((const void*)k_scan_coop, hipFuncAttributeMaxDynamicSharedMemorySize, SCAN_LDS);
  {
    void* xw_p = (void*)xw; void* whh_p = (void*)gru_Whh; void* bhh_p = (void*)gru_bhh;
    void* ha_p = (void*)h_all; void* hs_p = (void*)hsteps;
    void* wd_p = (void*)dense_W; void* wb_p = (void*)Wb;
    int wbf = use_wbf ? 1 : 0;
    void* enc_p = (void*)enc; void* aw_p = (void*)attn_W; void* ep_p = (void*)enc_proj;
    void* args[] = {&xw_p, &whh_p, &bhh_p, &ha_p, &hs_p, &wd_p, &wb_p, &wbf,
                    &enc_p, &aw_p, &ep_p};
    (void)hipLaunchCooperativeKernel((const void*)k_scan_coop, dim3(SCAN_BLOCKS_L), dim3(SCAN_THREADS),
                                     args, SCAN_LDS, stream);
  }

  // hw_attn GEMM: A = hsteps[0..63] (bf16 h before each step), B = attn_W[:, E:]
  k_sgemm<Hh, (Ee+Hh)><<<16*4, 256, SG_LDS, stream>>>(hsteps, attn_W + Ee, attn_b, hw_attn, Hh);
  k_score<<<Tt*Bb, 64, 0, stream>>>(hw_attn, enc_proj, enc, v_W, w_out, c_all);
  k_abuild<<<Tt*Bb, 256, 0, stream>>>(input_data, c_all, embedding, h_all, Abf);

  (void)hipFuncSetAttribute((const void*)k_gemm7<1>, hipFuncAttributeMaxDynamicSharedMemorySize, GEMM_LDS);
  (void)hipFuncSetAttribute((const void*)k_gemm7<0>, hipFuncAttributeMaxDynamicSharedMemorySize, GEMM_LDS);
  if (use_wbf){
    k_gemm7<1><<<16*((Vv + BN - 1)/BN), 256, GEMM_LDS, stream>>>(Abf, (const void*)Wb, dense_b, pred, partials);
  } else {
    k_gemm7<0><<<16*((Vv + BN - 1)/BN), 256, GEMM_LDS, stream>>>(Abf, (const void*)dense_W, dense_b, pred, partials);
  }

  k_lsecomb<<<Tt*Bb/4, 256, 0, stream>>>(partials, lse);
  k_sub<<<Tt*Bb, 256, 0, stream>>>(pred, lse);
  k_hT<<<64, 256, 0, stream>>>(h_all, hT_out);
}